// Round 1
// baseline (85.318 us; speedup 1.0000x reference)
//
#include <hip/hip_runtime.h>

// SpanNERDecoder: B=4, S=512, D=768, L=10, E=25, C=9, N=5075 spans.
// scores[b,n,c] = max_{p in [st,en)} we[b,p,:] . W[:D,c]  +  (len_embed[len] . W[D:,c] + bias[c])
//
// One wave per (b, start). Running-max over span lengths => 10 row loads per wave.
// W fragment (12 dims x 9 classes) kept in registers; len-embedding term folded
// into a 10x9 LDS table computed once per block.

#define SS 512
#define DD 768
#define LL 10
#define EE 25
#define CC 9
#define NSPANS 5075
#define BB 4

__global__ __launch_bounds__(256) void spanner_kernel(
    const float* __restrict__ we,    // [B,S,D]
    const float* __restrict__ lene,  // [L,E]
    const float* __restrict__ W,     // [D+E, C]
    const float* __restrict__ bias,  // [C]
    float* __restrict__ out)         // [B,N,C]
{
    __shared__ float lenW[LL][CC];
    const int t = threadIdx.x;

    // Per-block: fold len_embed @ W[D:,:] + bias into 10x9 table.
    if (t < LL * CC) {
        const int l = t / CC, c = t % CC;
        float s = bias[c];
#pragma unroll
        for (int e = 0; e < EE; ++e)
            s += lene[l * EE + e] * W[(DD + e) * CC + c];
        lenW[l][c] = s;
    }
    __syncthreads();

    const int lane = t & 63;
    const int gid  = blockIdx.x * 4 + (t >> 6);   // 0..2047 == B*S
    const int b    = gid >> 9;                    // /512
    const int i    = gid & (SS - 1);              // start position
    const int cnt  = min(LL, SS - i);             // spans for this start
    const int base = (i <= SS - LL + 1) ? i * LL
                     : (NSPANS - ((SS - i) * (SS + 1 - i)) / 2);

    // W fragment in registers: lane owns dims d = c0*256 + lane*4 + q.
    float Wr[3][4][CC];
#pragma unroll
    for (int c0 = 0; c0 < 3; ++c0)
#pragma unroll
        for (int q = 0; q < 4; ++q) {
            const int d = c0 * 256 + lane * 4 + q;
#pragma unroll
            for (int c = 0; c < CC; ++c)
                Wr[c0][q][c] = W[d * CC + c];
        }

    const float4* rowbase = reinterpret_cast<const float4*>(we) + (size_t)(b * SS) * (DD / 4);

    // Prefetch row i.
    float4 r0, r1, r2;
    {
        const float4* rp = rowbase + (size_t)i * (DD / 4);
        r0 = rp[lane]; r1 = rp[64 + lane]; r2 = rp[128 + lane];
    }

    float m[3][4];
#pragma unroll
    for (int c0 = 0; c0 < 3; ++c0)
#pragma unroll
        for (int q = 0; q < 4; ++q) m[c0][q] = -INFINITY;

    float* const outb = out + ((size_t)b * NSPANS + base) * CC;

#pragma unroll
    for (int k = 0; k < LL; ++k) {
        if (k >= cnt) break;

        // Fold current row into running max (consumes r0..r2).
        {
            const float* f;
            f = (const float*)&r0;
#pragma unroll
            for (int q = 0; q < 4; ++q) m[0][q] = fmaxf(m[0][q], f[q]);
            f = (const float*)&r1;
#pragma unroll
            for (int q = 0; q < 4; ++q) m[1][q] = fmaxf(m[1][q], f[q]);
            f = (const float*)&r2;
#pragma unroll
            for (int q = 0; q < 4; ++q) m[2][q] = fmaxf(m[2][q], f[q]);
        }

        // Issue next row load early so it overlaps dot+reduce below.
        if (k + 1 < cnt) {
            const float4* rp = rowbase + (size_t)(i + k + 1) * (DD / 4);
            r0 = rp[lane]; r1 = rp[64 + lane]; r2 = rp[128 + lane];
        }

        // Per-lane partial dot: 12 dims x 9 classes.
        float acc[CC];
#pragma unroll
        for (int c = 0; c < CC; ++c) acc[c] = 0.0f;
#pragma unroll
        for (int c0 = 0; c0 < 3; ++c0)
#pragma unroll
            for (int q = 0; q < 4; ++q)
#pragma unroll
                for (int c = 0; c < CC; ++c)
                    acc[c] = fmaf(m[c0][q], Wr[c0][q][c], acc[c]);

        // 6-step butterfly: all lanes end with the full 768-dim sums.
#pragma unroll
        for (int mask = 1; mask < 64; mask <<= 1)
#pragma unroll
            for (int c = 0; c < CC; ++c)
                acc[c] += __shfl_xor(acc[c], mask, 64);

        // Lane c stores class c (static-index select chain; no scratch).
        float v = acc[0];
        v = (lane == 1) ? acc[1] : v;
        v = (lane == 2) ? acc[2] : v;
        v = (lane == 3) ? acc[3] : v;
        v = (lane == 4) ? acc[4] : v;
        v = (lane == 5) ? acc[5] : v;
        v = (lane == 6) ? acc[6] : v;
        v = (lane == 7) ? acc[7] : v;
        v = (lane == 8) ? acc[8] : v;
        if (lane < CC)
            outb[(size_t)k * CC + lane] = v + lenW[k][lane];
    }
}

extern "C" void kernel_launch(void* const* d_in, const int* in_sizes, int n_in,
                              void* d_out, int out_size, void* d_ws, size_t ws_size,
                              hipStream_t stream) {
    const float* we   = (const float*)d_in[0];
    const float* lene = (const float*)d_in[1];
    const float* W    = (const float*)d_in[2];
    const float* bias = (const float*)d_in[3];
    float* out        = (float*)d_out;

    // 2048 waves = B*S; 4 waves per 256-thread block -> 512 blocks.
    spanner_kernel<<<512, 256, 0, stream>>>(we, lene, W, bias, out);
}

// Round 4
// 79.560 us; speedup vs baseline: 1.0724x; 1.0724x over previous
//
#include <hip/hip_runtime.h>

// SpanNERDecoder: B=4, S=512, D=768, L=10, E=25, C=9, N=5075 spans.
// scores[b,n,c] = max_{p in [st,en)} we[b,p,:] . W[:D,c] + (len_embed[len] . W[D:,c] + b[c])
//
// One wave per (b, start). Running max over span length -> 10 row loads/wave.
// W fragment (12 dims x 9 classes) in registers. Cross-lane dot reduction is
// batched 5 spans at a time (45 independent chains) and uses DPP for masks
// 1/2/4/8 (quad_perm, row_half_mirror, row_mirror) -> only xor16/xor32 touch DS.

#define SS 512
#define DD 768
#define LL 10
#define EE 25
#define CC 9
#define NSPANS 5075

__device__ __forceinline__ float wave_sum64(float v) {
    int x;
    // quad_perm [1,0,3,2] == xor1
    x = __builtin_amdgcn_update_dpp(0, __float_as_int(v), 0xB1, 0xF, 0xF, true);
    v += __int_as_float(x);
    // quad_perm [2,3,0,1] == xor2
    x = __builtin_amdgcn_update_dpp(0, __float_as_int(v), 0x4E, 0xF, 0xF, true);
    v += __int_as_float(x);
    // row_half_mirror == xor7 (acts as xor4: values already quad-uniform)
    x = __builtin_amdgcn_update_dpp(0, __float_as_int(v), 0x141, 0xF, 0xF, true);
    v += __int_as_float(x);
    // row_mirror == xor15 (acts as xor8: values already 8-uniform)
    x = __builtin_amdgcn_update_dpp(0, __float_as_int(v), 0x140, 0xF, 0xF, true);
    v += __int_as_float(x);
    v += __shfl_xor(v, 16, 64);
    v += __shfl_xor(v, 32, 64);
    return v;
}

__global__ __launch_bounds__(256, 2) void spanner_kernel(
    const float* __restrict__ we,    // [B,S,D]
    const float* __restrict__ lene,  // [L,E]
    const float* __restrict__ W,     // [D+E, C]
    const float* __restrict__ bias,  // [C]
    float* __restrict__ out)         // [B,N,C]
{
    __shared__ float lenW[LL][CC];
    const int t = threadIdx.x;

    // Fold len_embed @ W[D:,:] + bias into a 10x9 table (once per block).
    if (t < LL * CC) {
        const int l = t / CC, c = t % CC;
        float s = bias[c];
#pragma unroll
        for (int e = 0; e < EE; ++e)
            s += lene[l * EE + e] * W[(DD + e) * CC + c];
        lenW[l][c] = s;
    }
    __syncthreads();

    const int lane = t & 63;
    const int gid  = blockIdx.x * 4 + (t >> 6);   // 0..2047 == B*S
    const int b    = gid >> 9;
    const int i    = gid & (SS - 1);
    const int cnt  = min(LL, SS - i);
    const int base = (i <= SS - LL) ? i * LL
                     : (NSPANS - ((SS - i) * (SS - i + 1)) / 2);

    // W fragment: lane owns dims d = c0*256 + lane*4 + q. 36 contiguous floats
    // per c0 -> 9 float4 loads each.
    float Wr[3][4][CC];
#pragma unroll
    for (int c0 = 0; c0 < 3; ++c0) {
        const float4* wp = reinterpret_cast<const float4*>(W + (c0 * 256 + lane * 4) * CC);
        float4 wv[9];
#pragma unroll
        for (int j = 0; j < 9; ++j) wv[j] = wp[j];
        const float* wf = reinterpret_cast<const float*>(wv);
#pragma unroll
        for (int q = 0; q < 4; ++q)
#pragma unroll
            for (int c = 0; c < CC; ++c)
                Wr[c0][q][c] = wf[q * CC + c];
    }

    const float4* rowbase = reinterpret_cast<const float4*>(we) + (size_t)(b * SS) * (DD / 4);

    float4 r0 = rowbase[(size_t)i * (DD / 4) + lane];
    float4 r1 = rowbase[(size_t)i * (DD / 4) + 64 + lane];
    float4 r2 = rowbase[(size_t)i * (DD / 4) + 128 + lane];

    float m[3][4];
#pragma unroll
    for (int c0 = 0; c0 < 3; ++c0)
#pragma unroll
        for (int q = 0; q < 4; ++q) m[c0][q] = -INFINITY;

    float acc[5][CC];
    float res[LL];

#pragma unroll
    for (int k = 0; k < LL; ++k) {
        // Fold current row into the running max.
        {
            const float* f;
            f = (const float*)&r0;
#pragma unroll
            for (int q = 0; q < 4; ++q) m[0][q] = fmaxf(m[0][q], f[q]);
            f = (const float*)&r1;
#pragma unroll
            for (int q = 0; q < 4; ++q) m[1][q] = fmaxf(m[1][q], f[q]);
            f = (const float*)&r2;
#pragma unroll
            for (int q = 0; q < 4; ++q) m[2][q] = fmaxf(m[2][q], f[q]);
        }

        // Prefetch next row (clamped; spans past cnt are never stored).
        if (k + 1 < LL) {
            const int nr = min(i + k + 1, SS - 1);
            r0 = rowbase[(size_t)nr * (DD / 4) + lane];
            r1 = rowbase[(size_t)nr * (DD / 4) + 64 + lane];
            r2 = rowbase[(size_t)nr * (DD / 4) + 128 + lane];
        }

        // Per-lane partial dot: 12 dims x 9 classes.
        const int kk = k % 5;
#pragma unroll
        for (int c = 0; c < CC; ++c) acc[kk][c] = 0.0f;
#pragma unroll
        for (int c0 = 0; c0 < 3; ++c0)
#pragma unroll
            for (int q = 0; q < 4; ++q)
#pragma unroll
                for (int c = 0; c < CC; ++c)
                    acc[kk][c] = fmaf(m[c0][q], Wr[c0][q][c], acc[kk][c]);

        // Batched reduction every 5 spans: 45 independent chains.
        if (kk == 4) {
#pragma unroll
            for (int kb = 0; kb < 5; ++kb) {
                float s[CC];
#pragma unroll
                for (int c = 0; c < CC; ++c) s[c] = wave_sum64(acc[kb][c]);
                float v = s[0];
#pragma unroll
                for (int c = 1; c < CC; ++c) v = (lane == c) ? s[c] : v;
                res[k - 4 + kb] = v;
            }
        }
    }

    float* const outb = out + ((size_t)b * NSPANS + base) * CC;
    if (lane < CC) {
#pragma unroll
        for (int k = 0; k < LL; ++k)
            if (k < cnt) outb[k * CC + lane] = res[k] + lenW[k][lane];
    }
}

extern "C" void kernel_launch(void* const* d_in, const int* in_sizes, int n_in,
                              void* d_out, int out_size, void* d_ws, size_t ws_size,
                              hipStream_t stream) {
    const float* we   = (const float*)d_in[0];
    const float* lene = (const float*)d_in[1];
    const float* W    = (const float*)d_in[2];
    const float* bias = (const float*)d_in[3];
    float* out        = (float*)d_out;

    // 2048 waves = B*S; 4 waves per 256-thread block -> 512 blocks.
    spanner_kernel<<<512, 256, 0, stream>>>(we, lene, W, bias, out);
}